// Round 3
// baseline (999.869 us; speedup 1.0000x reference)
//
#include <hip/hip_runtime.h>
#include <math.h>

#define B_   8
#define T_   12
#define BT   96      // B*T
#define N_   1000
#define FIN  64
#define H_   8
#define FOUT 16
#define HF   128     // H*FOUT
#define E_   8000

typedef unsigned short u16;
typedef unsigned int   u32;

__device__ __forceinline__ float bf2f(u16 u) {
    return __uint_as_float(((u32)u) << 16);
}
__device__ __forceinline__ void unpack2(u32 q, float& lo, float& hi) {
    lo = __uint_as_float(q << 16);
    hi = __uint_as_float(q & 0xffff0000u);
}
__device__ __forceinline__ u16 f2bf(float f) {
    u32 x = __float_as_uint(f);
    u32 r = (x + 0x7fffu + ((x >> 16) & 1u)) >> 16;   // RNE
    return (u16)r;
}

// ---------------------------------------------------------------------------
// Workspace carve (float-element offsets). Total 7,725,504 floats ~ 29.5 MB.
// All float4-read regions are 16B aligned.
// ---------------------------------------------------------------------------
#define OFF_FLAGS   0        // 4 ints: [0]=bf16 tensors, [1]=int64 edges
#define OFF_AS      4        // 512
#define OFF_AT      516      // 512
#define OFF_GMAX    1028     // 4
#define OFF_PART    1032     // 3072
#define OFF_OFFS    4104     // 1004 ints
#define OFF_CSR     5108     // 8000 ints
#define OFF_SRCA    13108    // 8000 ints
#define OFF_TRGA    21108    // 8000 ints
#define OFF_WP32    29108    // 8192
#define OFF_WS32    37300    // 8192
#define OFF_SSRC    45504    // 768000
#define OFF_STRG    813504   // 768000
#define OFF_X32     1581504  // 6144000 -> end 7725504

// ---------------------------------------------------------------------------
// K-1: runtime layout detection.
//  flag0 (bf16): view x's first 256 u32 words; bits[14:7] of the low u16 are a
//  bf16 exponent (always ~[95,140] or 0 for N(0,1) data) iff the buffer is
//  bf16; for fp32 those bits are uniform mantissa bits (~18% hit rate).
//  flag1 (int64 edges): OR of odd u32 words of the first 16000 words is 0 iff
//  the buffer is int64 (high halves of values < 1000); for int32 it ORs actual
//  node ids (nonzero w.p. ~1).
// ---------------------------------------------------------------------------
__global__ __launch_bounds__(256) void k_detect(const u32* __restrict__ xw,
                                                const u32* __restrict__ ew,
                                                int* __restrict__ flags)
{
    __shared__ int votes;
    __shared__ u32 orAcc;
    const int tid = threadIdx.x;
    if (tid == 0) { votes = 0; orAcc = 0u; }
    __syncthreads();

    const u32 w = xw[tid];
    const int e = (int)((w >> 7) & 0xFFu);
    if (e == 0 || (e >= 95 && e <= 140)) atomicAdd(&votes, 1);

    u32 o = 0;
    for (int i = 2 * tid + 1; i < 16000; i += 512) o |= ew[i];
    atomicOr(&orAcc, o);
    __syncthreads();

    if (tid == 0) {
        flags[0] = (votes >= 160) ? 1 : 0;
        flags[1] = (orAcc == 0u) ? 1 : 0;
    }
}

// ---------------------------------------------------------------------------
// K0a: canonicalize x -> fp32. 3000 blocks x 256 thr, 8 elems/thread.
// ---------------------------------------------------------------------------
__global__ __launch_bounds__(256) void k_convX(const void* __restrict__ xin,
                                               const int* __restrict__ flags,
                                               float* __restrict__ x32)
{
    const int i = blockIdx.x * 256 + threadIdx.x;   // [0, 768000)
    if (flags[0]) {
        uint4 q = ((const uint4*)xin)[i];           // 8 bf16
        float4 r0, r1;
        unpack2(q.x, r0.x, r0.y); unpack2(q.y, r0.z, r0.w);
        unpack2(q.z, r1.x, r1.y); unpack2(q.w, r1.z, r1.w);
        ((float4*)x32)[2 * i]     = r0;
        ((float4*)x32)[2 * i + 1] = r1;
    } else {
        uint4 q0 = ((const uint4*)xin)[2 * i];      // 8 fp32 passthrough
        uint4 q1 = ((const uint4*)xin)[2 * i + 1];
        ((uint4*)x32)[2 * i]     = q0;
        ((uint4*)x32)[2 * i + 1] = q1;
    }
}

// ---------------------------------------------------------------------------
// K0b: canonicalize W_proj / W_skip -> fp32 and fold attention vectors:
//      aS[h][k] = sum_f a_src[h,f] * Wp[h*16+f, k]   (likewise aT)
// ---------------------------------------------------------------------------
__global__ __launch_bounds__(256) void k_prep(const void* __restrict__ Wp,
                                              const void* __restrict__ Ws,
                                              const void* __restrict__ as_,
                                              const void* __restrict__ at_,
                                              const int* __restrict__ flags,
                                              float* __restrict__ Wp32,
                                              float* __restrict__ Ws32,
                                              float* __restrict__ aS,
                                              float* __restrict__ aT)
{
    const int tid = threadIdx.x;
    const bool bf = flags[0] != 0;

    for (int i = tid; i < HF * FIN; i += 256) {
        Wp32[i] = bf ? bf2f(((const u16*)Wp)[i]) : ((const float*)Wp)[i];
        Ws32[i] = bf ? bf2f(((const u16*)Ws)[i]) : ((const float*)Ws)[i];
    }
    __syncthreads();

    for (int q = tid; q < H_ * FIN; q += 256) {
        const int h = q >> 6, k = q & 63;
        float s1 = 0.f, s2 = 0.f;
#pragma unroll
        for (int f = 0; f < FOUT; f++) {
            const float w = Wp32[(h * FOUT + f) * FIN + k];
            const float a1 = bf ? bf2f(((const u16*)as_)[h * FOUT + f])
                                : ((const float*)as_)[h * FOUT + f];
            const float a2 = bf ? bf2f(((const u16*)at_)[h * FOUT + f])
                                : ((const float*)at_)[h * FOUT + f];
            s1 = fmaf(a1, w, s1);
            s2 = fmaf(a2, w, s2);
        }
        aS[q] = s1;
        aT[q] = s2;
    }
}

// ---------------------------------------------------------------------------
// K0c: normalize edge_index -> int32 srcA/trgA (handles int64 or int32).
// ---------------------------------------------------------------------------
__global__ __launch_bounds__(256) void k_edges(const u32* __restrict__ ew,
                                               const int* __restrict__ flags,
                                               int* __restrict__ srcA,
                                               int* __restrict__ trgA)
{
    const int e = blockIdx.x * 256 + threadIdx.x;
    if (e >= E_) return;
    int s, t;
    if (flags[1]) {                    // int64: low words at 2*idx
        s = (int)ew[2 * e];
        t = (int)ew[2 * (E_ + e)];
    } else {                           // int32
        s = (int)ew[e];
        t = (int)ew[E_ + e];
    }
    srcA[e] = s;
    trgA[e] = t;
}

// ---------------------------------------------------------------------------
// K1: build CSR (edges grouped by target). Single block, 1024 threads.
// ---------------------------------------------------------------------------
__global__ __launch_bounds__(1024) void k_csr(const int* __restrict__ srcA,
                                              const int* __restrict__ trgA,
                                              int* __restrict__ offs,
                                              int* __restrict__ csr)
{
    __shared__ int cnt[1024];
    __shared__ int scan[1024];
    __shared__ int cursor[1024];
    const int tid = threadIdx.x;

    cnt[tid] = 0;
    __syncthreads();
    for (int e = tid; e < E_; e += 1024)
        atomicAdd(&cnt[trgA[e]], 1);
    __syncthreads();

    scan[tid] = cnt[tid];
    __syncthreads();
    for (int d = 1; d < 1024; d <<= 1) {
        int t = (tid >= d) ? scan[tid - d] : 0;
        __syncthreads();
        scan[tid] += t;
        __syncthreads();
    }
    int excl = (tid == 0) ? 0 : scan[tid - 1];
    cursor[tid] = excl;
    if (tid < N_) offs[tid] = excl;
    if (tid == 0) offs[N_] = E_;
    __syncthreads();

    for (int e = tid; e < E_; e += 1024) {
        int t = trgA[e];
        int pos = atomicAdd(&cursor[t], 1);
        csr[pos] = srcA[e];
    }
}

// ---------------------------------------------------------------------------
// K2: per-node scores.  s_src[n,h] = aS[h]·x[n],  s_trg[n,h] = aT[h]·x[n]
// 256 thr = 16 nodes × 16 dots (d<8 -> s_src head d, else s_trg head d-8)
// ---------------------------------------------------------------------------
__global__ __launch_bounds__(256) void k_scores(const float* __restrict__ x32,
                                                const float* __restrict__ aS,
                                                const float* __restrict__ aT,
                                                float* __restrict__ s_src,
                                                float* __restrict__ s_trg)
{
    const int tid = threadIdx.x;
    const int n = blockIdx.x * 16 + (tid >> 4);
    if (n >= N_) return;
    const int d = tid & 15;
    const int h = d & 7;
    const int node = blockIdx.y * N_ + n;

    const float4* ar = reinterpret_cast<const float4*>((d < 8 ? aS : aT) + h * FIN);
    const float4* xr = reinterpret_cast<const float4*>(x32 + (size_t)node * FIN);

    float acc = 0.f;
#pragma unroll
    for (int i = 0; i < 16; i++) {
        const float4 xv = xr[i], av = ar[i];
        acc = fmaf(xv.x, av.x, acc);
        acc = fmaf(xv.y, av.y, acc);
        acc = fmaf(xv.z, av.z, acc);
        acc = fmaf(xv.w, av.w, acc);
    }
    (d < 8 ? s_src : s_trg)[node * H_ + h] = acc;
}

// ---------------------------------------------------------------------------
// K3/K3b: global max of leaky_relu scores
// ---------------------------------------------------------------------------
__global__ __launch_bounds__(256) void k_max(const int* __restrict__ srcA,
                                             const int* __restrict__ trgA,
                                             const float* __restrict__ s_src,
                                             const float* __restrict__ s_trg,
                                             float* __restrict__ partial)
{
    const int e  = blockIdx.x * 256 + threadIdx.x;
    const int bt = blockIdx.y;
    float m = -INFINITY;
    if (e < E_) {
        const int s = srcA[e], g = trgA[e];
        const float* ps = s_src + (size_t)(bt * N_ + s) * H_;
        const float* pt = s_trg + (size_t)(bt * N_ + g) * H_;
#pragma unroll
        for (int h = 0; h < H_; h++) {
            float sc = ps[h] + pt[h];
            sc = sc > 0.f ? sc : 0.2f * sc;
            m = fmaxf(m, sc);
        }
    }
#pragma unroll
    for (int d = 32; d >= 1; d >>= 1) m = fmaxf(m, __shfl_xor(m, d, 64));
    __shared__ float wm[4];
    const int tid = threadIdx.x;
    if ((tid & 63) == 0) wm[tid >> 6] = m;
    __syncthreads();
    if (tid == 0)
        partial[bt * gridDim.x + blockIdx.x] =
            fmaxf(fmaxf(wm[0], wm[1]), fmaxf(wm[2], wm[3]));
}

__global__ __launch_bounds__(1024) void k_max2(const float* __restrict__ partial,
                                               float* __restrict__ gmax, int np)
{
    const int tid = threadIdx.x;
    float m = -INFINITY;
    for (int i = tid; i < np; i += 1024) m = fmaxf(m, partial[i]);
#pragma unroll
    for (int d = 32; d >= 1; d >>= 1) m = fmaxf(m, __shfl_xor(m, d, 64));
    __shared__ float wm[16];
    if ((tid & 63) == 0) wm[tid >> 6] = m;
    __syncthreads();
    if (tid == 0) {
        float r = -INFINITY;
#pragma unroll
        for (int i = 0; i < 16; i++) r = fmaxf(r, wm[i]);
        *gmax = r;
    }
}

// ---------------------------------------------------------------------------
// K4: fused aggregate + projection + skip + ELU.
// Identity: sum_e ex*proj[src] = Wp @ (sum_e ex*x[src])  -> aggregate in
// x-space (y[h][k], 8x64 per node), then one Wp matvec per node.
// 128 threads: j -> out (h=j>>4, f=j&15). Thread j owns y rows hb..hb+3
// (hb=(j>>6)*4) at column k6=j&63. No barriers in the edge loop.
// ---------------------------------------------------------------------------
__global__ __launch_bounds__(128) void k_out(const float* __restrict__ x32,
                                             const float* __restrict__ Wp32,
                                             const float* __restrict__ Ws32,
                                             const float* __restrict__ s_src,
                                             const float* __restrict__ s_trg,
                                             const int* __restrict__ offs,
                                             const int* __restrict__ csr,
                                             const float* __restrict__ gmaxp,
                                             const int* __restrict__ flags,
                                             void* __restrict__ out)
{
    const int n  = blockIdx.x;
    const int bt = blockIdx.y;
    const int j  = threadIdx.x;
    const int node = bt * N_ + n;

    __shared__ float xt[FIN];
    __shared__ float ys[8 * 66];   // row stride 66 -> conflict-free final dot

    if (j < FIN) xt[j] = x32[(size_t)node * FIN + j];
    __syncthreads();

    // skip = W_skip[j,:] . x[node,:]
    const float4* Wv = reinterpret_cast<const float4*>(Ws32 + j * FIN);
    float skip = 0.f;
#pragma unroll
    for (int i = 0; i < 16; i++) {
        const float4 w = Wv[i];
        const int k = i * 4;
        skip = fmaf(w.x, xt[k + 0], skip);
        skip = fmaf(w.y, xt[k + 1], skip);
        skip = fmaf(w.z, xt[k + 2], skip);
        skip = fmaf(w.w, xt[k + 3], skip);
    }

    const int hb   = (j >> 6) * 4;    // 0 or 4
    const int k6   = j & 63;
    const int mden = (j >> 4) & 3;    // which owned head is my output head
    const float g  = *gmaxp;

    const float4 st4 = *reinterpret_cast<const float4*>(&s_trg[(size_t)node * H_ + hb]);
    const float stm[4] = {st4.x, st4.y, st4.z, st4.w};

    const int e0 = offs[n], e1 = offs[n + 1];
    float y0 = 0.f, y1 = 0.f, y2 = 0.f, y3 = 0.f, den = 0.f;

    for (int i = e0; i < e1; i++) {
        const int s  = csr[i];
        const int sn = bt * N_ + s;
        const float xv = x32[(size_t)sn * FIN + k6];
        const float4 ss4 = *reinterpret_cast<const float4*>(&s_src[(size_t)sn * H_ + hb]);

        float sc0 = ss4.x + stm[0]; sc0 = sc0 > 0.f ? sc0 : 0.2f * sc0;
        float sc1 = ss4.y + stm[1]; sc1 = sc1 > 0.f ? sc1 : 0.2f * sc1;
        float sc2 = ss4.z + stm[2]; sc2 = sc2 > 0.f ? sc2 : 0.2f * sc2;
        float sc3 = ss4.w + stm[3]; sc3 = sc3 > 0.f ? sc3 : 0.2f * sc3;
        const float ex0 = __expf(sc0 - g);
        const float ex1 = __expf(sc1 - g);
        const float ex2 = __expf(sc2 - g);
        const float ex3 = __expf(sc3 - g);
        y0 = fmaf(ex0, xv, y0);
        y1 = fmaf(ex1, xv, y1);
        y2 = fmaf(ex2, xv, y2);
        y3 = fmaf(ex3, xv, y3);
        den += (mden == 0) ? ex0 : (mden == 1) ? ex1 : (mden == 2) ? ex2 : ex3;
    }

    ys[(hb + 0) * 66 + k6] = y0;
    ys[(hb + 1) * 66 + k6] = y1;
    ys[(hb + 2) * 66 + k6] = y2;
    ys[(hb + 3) * 66 + k6] = y3;
    __syncthreads();

    // acc = Wp[j,:] . y[h]
    const int h = j >> 4;
    const float* yr = &ys[h * 66];
    const float4* Wpv = reinterpret_cast<const float4*>(Wp32 + j * FIN);
    float acc = 0.f;
#pragma unroll
    for (int i = 0; i < 16; i++) {
        const float4 w = Wpv[i];
        const int k = i * 4;
        acc = fmaf(w.x, yr[k + 0], acc);
        acc = fmaf(w.y, yr[k + 1], acc);
        acc = fmaf(w.z, yr[k + 2], acc);
        acc = fmaf(w.w, yr[k + 3], acc);
    }

    float o = acc / (den + 1e-16f) + skip;
    o = o > 0.f ? o : expm1f(o);            // ELU (alpha=1)

    const size_t oi = (size_t)node * HF + j;
    if (flags[0]) ((u16*)out)[oi] = f2bf(o);
    else          ((float*)out)[oi] = o;
}

// ---------------------------------------------------------------------------
extern "C" void kernel_launch(void* const* d_in, const int* in_sizes, int n_in,
                              void* d_out, int out_size, void* d_ws, size_t ws_size,
                              hipStream_t stream)
{
    const void* x   = d_in[0];
    const u32*  ew  = (const u32*)d_in[1];
    const void* Wp  = d_in[2];
    const void* as_ = d_in[3];
    const void* at_ = d_in[4];
    const void* Ws  = d_in[5];

    float* ws      = (float*)d_ws;
    int*   flags   = (int*)(ws + OFF_FLAGS);
    float* aS      = ws + OFF_AS;
    float* aT      = ws + OFF_AT;
    float* gmax    = ws + OFF_GMAX;
    float* partial = ws + OFF_PART;
    int*   offs    = (int*)(ws + OFF_OFFS);
    int*   csr     = (int*)(ws + OFF_CSR);
    int*   srcA    = (int*)(ws + OFF_SRCA);
    int*   trgA    = (int*)(ws + OFF_TRGA);
    float* Wp32    = ws + OFF_WP32;
    float* Ws32    = ws + OFF_WS32;
    float* s_src   = ws + OFF_SSRC;
    float* s_trg   = ws + OFF_STRG;
    float* x32     = ws + OFF_X32;

    k_detect<<<1, 256, 0, stream>>>((const u32*)x, ew, flags);
    k_convX <<<3000, 256, 0, stream>>>(x, flags, x32);
    k_prep  <<<1, 256, 0, stream>>>(Wp, Ws, as_, at_, flags, Wp32, Ws32, aS, aT);
    k_edges <<<32, 256, 0, stream>>>(ew, flags, srcA, trgA);
    k_csr   <<<1, 1024, 0, stream>>>(srcA, trgA, offs, csr);
    k_scores<<<dim3((N_ + 15) / 16, BT), 256, 0, stream>>>(x32, aS, aT, s_src, s_trg);
    k_max   <<<dim3(32, BT), 256, 0, stream>>>(srcA, trgA, s_src, s_trg, partial);
    k_max2  <<<1, 1024, 0, stream>>>(partial, gmax, 32 * BT);
    k_out   <<<dim3(N_, BT), 128, 0, stream>>>(x32, Wp32, Ws32, s_src, s_trg,
                                               offs, csr, gmax, flags, d_out);
}